// Round 15
// baseline (2102.625 us; speedup 1.0000x reference)
//
#include <hip/hip_runtime.h>

// promptKT 4-layer transformer, MI355X bf16 MFMA implementation.
// Adaptive workspace: big path ~279 MB (full FFN hidden), small path ~191 MB.
// GEMM (R10/R12-verified, frozen): 256x256, BK=64, 8 waves, 1 barrier/K-tile,
// pipelined A/B frags via LDS, XOR-chunk swizzle, fused V head-transpose (VTR).
// fattn (R15): QBLK=256 — each wave owns 2x16 Q-rows sharing each K/V tile
// (tiles/block 20->12, barriers -40%); T14 async-stage, T13 defer-max, T5 setprio.
// R14: bf16 residual master on big path; final LN also writes f32 d_out.

#define DEV static __device__ __forceinline__

typedef unsigned short u16;
typedef __attribute__((ext_vector_type(4))) unsigned short u16x4;
typedef __attribute__((ext_vector_type(8))) unsigned short u16x8;
typedef __attribute__((ext_vector_type(8))) short bf16x8;
typedef __attribute__((ext_vector_type(4))) float f32x4;

static constexpr int Bn = 32, Sn = 512, Dn = 1024, Hn = 16, Ln = 4, DFFn = 4096, DKn = 64;
static constexpr int Mn = Bn * Sn; // 16384 rows

DEV u16 f2bf(float f) {
  unsigned u = __float_as_uint(f);
  u += 0x7FFFu + ((u >> 16) & 1u);   // round-nearest-even (no NaN inputs here)
  return (u16)(u >> 16);
}
DEV float bf2f(u16 v) { return __uint_as_float((unsigned)v << 16); }

DEV void gload_lds16(const void* g, void* l) {
  __builtin_amdgcn_global_load_lds((const __attribute__((address_space(1))) void*)g,
                                   (__attribute__((address_space(3))) void*)l, 16, 0, 0);
}

DEV void barf() {
  asm volatile("" ::: "memory");
  __builtin_amdgcn_s_barrier();
  asm volatile("" ::: "memory");
}

// ---------------- positional embedding + input casts ----------------
// WX: also write f32 x master (small-ws path only).
template<int WX>
__global__ __launch_bounds__(256) void pe_add_kernel(
    const float* __restrict__ q, const float* __restrict__ qa,
    float* __restrict__ x, u16* __restrict__ xb, u16* __restrict__ yb)
{
  size_t i4 = ((size_t)blockIdx.x * 256 + threadIdx.x) * 4;
  int d0 = (int)(i4 & (Dn - 1));
  int s  = (int)((i4 >> 10) & (Sn - 1));
  float p = (float)s;
  const float LC = 0.0089944730195f;  // ln(10000)/1024
  float a0 = p * expf(-LC * (float)d0);
  float a2 = p * expf(-LC * (float)(d0 + 2));
  float pe0 = sinf(a0), pe1 = cosf(a0), pe2 = sinf(a2), pe3 = cosf(a2);
  const float4 qv = *(const float4*)(q + i4);
  const float4 av = *(const float4*)(qa + i4);
  float x0 = qv.x + pe0, x1 = qv.y + pe1, x2 = qv.z + pe2, x3 = qv.w + pe3;
  float y0 = av.x + pe0, y1 = av.y + pe1, y2 = av.z + pe2, y3 = av.w + pe3;
  if (WX) *(float4*)(x + i4) = make_float4(x0, x1, x2, x3);
  u16x4 xv4 = { f2bf(x0), f2bf(x1), f2bf(x2), f2bf(x3) };
  u16x4 yv4 = { f2bf(y0), f2bf(y1), f2bf(y2), f2bf(y3) };
  *(u16x4*)(xb + i4) = xv4;
  *(u16x4*)(yb + i4) = yv4;
}

// ---------------- weight transpose + f32->bf16 cast ----------------
// in: (R, C) f32 row-major ; out: (C, R) bf16 row-major
__global__ __launch_bounds__(256) void transpose_cast_kernel(
    const float* __restrict__ in, u16* __restrict__ out, int R, int C)
{
  __shared__ float t[32][33];
  int tx = threadIdx.x & 31, ty = threadIdx.x >> 5;
  int c0 = blockIdx.x * 32, r0 = blockIdx.y * 32;
  #pragma unroll
  for (int i = 0; i < 4; ++i)
    t[ty + i * 8][tx] = in[(size_t)(r0 + ty + i * 8) * C + c0 + tx];
  __syncthreads();
  #pragma unroll
  for (int i = 0; i < 4; ++i) {
    int rr = ty + i * 8;
    out[(size_t)(c0 + rr) * R + r0 + tx] = f2bf(t[tx][rr]);
  }
}

// 3x (1024,1024) transposes in one dispatch (z selects which weight)
__global__ __launch_bounds__(256) void transpose_cast3_kernel(
    const float* __restrict__ i0, const float* __restrict__ i1, const float* __restrict__ i2,
    u16* __restrict__ o0, u16* __restrict__ o1, u16* __restrict__ o2)
{
  const int z = blockIdx.z;
  const float* in = (z == 0) ? i0 : (z == 1) ? i1 : i2;
  u16* out = (z == 0) ? o0 : (z == 1) ? o1 : o2;
  __shared__ float t[32][33];
  int tx = threadIdx.x & 31, ty = threadIdx.x >> 5;
  int c0 = blockIdx.x * 32, r0 = blockIdx.y * 32;
  #pragma unroll
  for (int i = 0; i < 4; ++i)
    t[ty + i * 8][tx] = in[(size_t)(r0 + ty + i * 8) * Dn + c0 + tx];
  __syncthreads();
  #pragma unroll
  for (int i = 0; i < 4; ++i) {
    int rr = ty + i * 8;
    out[(size_t)(c0 + rr) * Dn + r0 + tx] = f2bf(t[tx][rr]);
  }
}

// ------------- bf16 GEMM 256x256, BK=64, 8 waves, 1-barrier/tile pipelined -------------
// C(M,N) = A(M,K) * BT(N,K)^T (+bias)(+relu)(+acc). M,N mult of 256, K of 64.
// LDS: 2 bufs x (A[256][64] + B[256][64]) bf16 = 128 KB, 1 block/CU.
// XOR-chunk swizzle: phys 16B-chunk c of row r holds logical chunk c^(r&7)
// (linear gload_lds dest + inverse-swizzled global source + swizzled ds_read).
// DUAL: blockIdx.z==1 switches to (A2,BT2,bias2,Cout2). VTR: z==1 plane writes
// head-transposed (B,H,DK,S) bf16 (fused vtrans).
template<int BIAS, int RELU, int F32OUT, int ACC, int DUAL = 0, int VTR = 0>
__global__ __launch_bounds__(512, 2) void gemm8p_kernel(
    const u16* __restrict__ A, int lda,
    const u16* __restrict__ BT, int ldb,
    const float* __restrict__ bias,
    void* __restrict__ Cout, int ldc,
    int M, int N, int K,
    const u16* A2 = nullptr, const u16* BT2 = nullptr,
    const float* bias2 = nullptr, void* Cout2 = nullptr)
{
  if (DUAL && blockIdx.z) { A = A2; BT = BT2; bias = bias2; Cout = Cout2; }
  const bool vtr = VTR && DUAL && blockIdx.z;
  __shared__ u16 lds[2][2][16384];   // [buf][A=0|B=1][256 rows x 64 k]
  const int tid = threadIdx.x;
  const int lane = tid & 63, wid = tid >> 6;
  const int g = lane >> 4, r16 = lane & 15;
  const int wm = wid >> 2, wn = wid & 3;   // 2(M) x 4(N) waves; per-wave C: 128x64

  // XCD-chunked block swizzle (bijective; per-z-plane grid size % 8 == 0)
  const int nwgx = N >> 8;
  const int nwg = gridDim.x * gridDim.y;
  const int flat = blockIdx.y * gridDim.x + blockIdx.x;
  const int cpx = nwg >> 3;
  const int logical = (flat & 7) * cpx + (flat >> 3);
  const int n0 = (logical % nwgx) << 8;
  const int m0 = (logical / nwgx) << 8;

  f32x4 acc[8][4];
  #pragma unroll
  for (int i = 0; i < 8; ++i)
    #pragma unroll
    for (int j = 0; j < 4; ++j) acc[i][j] = (f32x4){0.f, 0.f, 0.f, 0.f};

  // staging: thread covers (row rr, 16B chunk ck); source col chunk = ck ^ (rr&7)
  const int rr = tid >> 3, ck = tid & 7;
  const int scol = ((ck ^ (rr & 7)) << 3);
  const u16* Asrc = A  + (size_t)(m0 + rr) * lda + scol;
  const u16* Bsrc = BT + (size_t)(n0 + rr) * ldb + scol;
  const int eds = rr * 64 + ck * 8;       // linear element offset (== tid*8)
  const size_t a64 = (size_t)64 * lda, b64 = (size_t)64 * ldb;

  // unit h: 0 = A rows 0-127, 1 = A rows 128-255, 2 = B rows 0-127, 3 = B rows 128-255
  #define STG(p, h, t) do {                                                  \
    if ((h) < 2) {                                                           \
      const u16* s_ = Asrc + (size_t)((h) * 128) * lda + (t) * 64;           \
      gload_lds16(s_,       &lds[p][0][eds + (h) * 8192]);                   \
      gload_lds16(s_ + a64, &lds[p][0][eds + (h) * 8192 + 4096]);            \
    } else {                                                                 \
      const u16* s_ = Bsrc + (size_t)(((h) - 2) * 128) * ldb + (t) * 64;     \
      gload_lds16(s_,       &lds[p][1][eds + ((h) - 2) * 8192]);             \
      gload_lds16(s_ + b64, &lds[p][1][eds + ((h) - 2) * 8192 + 4096]);      \
    }                                                                        \
  } while (0)

  // ds_read swizzled chunk offsets (elements): frag (ks,g) -> chunk (ks*4+g)^(r16&7)
  const int c0 = ((g ^ (r16 & 7)) << 3);
  const int c1 = (((4 + g) ^ (r16 & 7)) << 3);
  const int arow = wm * 128 + r16;
  const int brow = wn * 64 + r16;

  #define LDA2(p, q, af) do {                                                        \
    af[0][0] = *(const bf16x8*)&lds[p][0][(arow + (2*(q))   * 16) * 64 + c0];        \
    af[0][1] = *(const bf16x8*)&lds[p][0][(arow + (2*(q))   * 16) * 64 + c1];        \
    af[1][0] = *(const bf16x8*)&lds[p][0][(arow + (2*(q)+1) * 16) * 64 + c0];        \
    af[1][1] = *(const bf16x8*)&lds[p][0][(arow + (2*(q)+1) * 16) * 64 + c1];        \
  } while (0)

  // ks-outer: 8 independent MFMAs between successive writes of the same acc
  #define MMQ(q, af, bf) do {                                                        \
    __builtin_amdgcn_s_setprio(1);                                                   \
    _Pragma("unroll")                                                                \
    for (int ks = 0; ks < 2; ++ks)                                                   \
      _Pragma("unroll")                                                              \
      for (int i2 = 0; i2 < 2; ++i2)                                                 \
        _Pragma("unroll")                                                            \
        for (int j = 0; j < 4; ++j)                                                  \
          acc[2*(q)+i2][j] = __builtin_amdgcn_mfma_f32_16x16x32_bf16(af[i2][ks], bf[j][ks], acc[2*(q)+i2][j], 0, 0, 0); \
    __builtin_amdgcn_s_setprio(0);                                                   \
  } while (0)

  const int nt = K >> 6;
  // prologue: stage tile 0 fully, drain, barrier
  STG(0, 0, 0); STG(0, 1, 0); STG(0, 2, 0); STG(0, 3, 0);
  asm volatile("s_waitcnt vmcnt(0)" ::: "memory");
  barf();

  for (int t = 0; t < nt; ++t) {
    const int p = t & 1;
    const bool pf = (t + 1 < nt);
    bf16x8 bf[4][2], af[2][2], ag[2][2];
    // B fragments (8 reads) + A quad 0 (4 reads); STG units interleaved for lead time
    #pragma unroll
    for (int j = 0; j < 4; ++j) {
      bf[j][0] = *(const bf16x8*)&lds[p][1][(brow + j * 16) * 64 + c0];
      bf[j][1] = *(const bf16x8*)&lds[p][1][(brow + j * 16) * 64 + c1];
    }
    LDA2(p, 0, af);
    if (pf) { STG(p ^ 1, 0, t + 1); STG(p ^ 1, 1, t + 1); }
    MMQ(0, af, bf);
    LDA2(p, 1, ag);           // overlaps MMQ(0) retire / MMQ(1) waits only these
    if (pf) STG(p ^ 1, 2, t + 1);
    MMQ(1, ag, bf);
    LDA2(p, 2, af);
    if (pf) STG(p ^ 1, 3, t + 1);
    MMQ(2, af, bf);
    LDA2(p, 3, ag);
    MMQ(3, ag, bf);
    // tile-end fences: all buf-p ds_reads complete (next tile's STG overwrites
    // buf p) and all U(t+1) staging landed (next tile reads buf p^1).
    asm volatile("s_waitcnt lgkmcnt(0)" ::: "memory");
    asm volatile("s_waitcnt vmcnt(0)" ::: "memory");
    barf();
  }
  #undef STG
  #undef LDA2
  #undef MMQ

  #pragma unroll
  for (int i = 0; i < 8; ++i) {
    const int rb = m0 + wm * 128 + i * 16 + 4 * g;
    #pragma unroll
    for (int j = 0; j < 4; ++j) {
      const int col = n0 + wn * 64 + j * 16 + r16;
      float badd = BIAS ? bias[col] : 0.f;
      if (vtr) {
        // head-transposed write: (B,H,DK,S), 4 consecutive s -> one u16x4
        u16x4 pk;
        #pragma unroll
        for (int r = 0; r < 4; ++r) pk[r] = f2bf(acc[i][j][r] + badd);
        const int h_ = col >> 6, dk = col & 63;
        const int b_ = rb >> 9, s0 = rb & (Sn - 1);
        *(u16x4*)&((u16*)Cout)[(((size_t)(b_ * Hn + h_) * DKn + dk) << 9) + s0] = pk;
      } else {
        #pragma unroll
        for (int r = 0; r < 4; ++r) {
          size_t off = (size_t)(rb + r) * ldc + col;
          float v = acc[i][j][r] + badd;
          if (RELU) v = fmaxf(v, 0.f);
          if (F32OUT) {
            float* Cf = (float*)Cout;
            if (ACC) v += Cf[off];
            Cf[off] = v;
          } else {
            ((u16*)Cout)[off] = f2bf(v);
          }
        }
      }
    }
  }
}

// ---------------- flash attention: strictly-causal softmax(QK^T/8)V ----------------
// Kb serves as both Q and K (kq_same). Vt is (B,H,DK,S). O is (B*S, D) bf16.
// Block: one (b,h) x 256 Q-rows; 8 waves x TWO 16-row groups (myrow, myrow+128)
// sharing each staged K/V tile. T14 async-stage, T13 defer-max THR=8, T5 setprio.
__global__ __launch_bounds__(512) void fattn_kernel(
    const u16* __restrict__ Kb, const u16* __restrict__ Vt, u16* __restrict__ O)
{
  __shared__ u16 kl[64][72];      // K tile: [kv][dk]
  __shared__ u16 vl[64][72];      // V tile: [dk][kv]
  __shared__ u16 pw[8][16][72];   // per-wave P staging: [q][kv] (reused per group)
  const int idx = blockIdx.x;     // B*H*2
  const int qt = idx & 1;
  const int h  = (idx >> 1) & 15;
  const int b  = idx >> 5;
  const int Q0 = qt * 256;
  const int tid = threadIdx.x;
  const int lane = tid & 63, w = tid >> 6;
  const int g = lane >> 4, r16 = lane & 15;

  // each wave owns rows myrow(grp) = Q0 + 128*grp + 16w .. +15
  bf16x8 qf[2][2];
  #pragma unroll
  for (int grp = 0; grp < 2; ++grp) {
    const u16* qrow = &Kb[(size_t)(b * Sn + Q0 + 128 * grp + 16 * w + r16) * Dn + h * DKn];
    qf[grp][0] = *(const bf16x8*)(qrow + 8 * g);
    qf[grp][1] = *(const bf16x8*)(qrow + 32 + 8 * g);
  }
  f32x4 oacc[2][4];
  float mrow[2][4], lrow[2][4];
  #pragma unroll
  for (int grp = 0; grp < 2; ++grp) {
    #pragma unroll
    for (int j = 0; j < 4; ++j) oacc[grp][j] = (f32x4){0.f, 0.f, 0.f, 0.f};
    #pragma unroll
    for (int r = 0; r < 4; ++r) { mrow[grp][r] = -1e30f; lrow[grp][r] = 0.f; }
  }

  const int srow = tid >> 3;          // 0..63
  const int scol = (tid & 7) * 8;
  const u16* kbase = Kb + (size_t)(b * Sn) * Dn + h * DKn;
  const u16* vbase = Vt + (size_t)(b * Hn + h) * DKn * Sn;
  const int ctmax = (Q0 + 254) >> 6;  // qt0: 3, qt1: 7

  // prologue: stage tile 0
  {
    u16x8 k0 = *(const u16x8*)&kbase[(size_t)srow * Dn + scol];
    u16x8 v0 = *(const u16x8*)&vbase[(size_t)srow * Sn + scol];
    *(u16x8*)&kl[srow][scol] = k0;
    *(u16x8*)&vl[srow][scol] = v0;
  }
  __syncthreads();

  for (int ct = 0; ct <= ctmax; ++ct) {
    // T14: issue next tile's loads now; consumed only after the next barrier.
    u16x8 kn, vn;
    const bool pf = (ct + 1 <= ctmax);
    if (pf) {
      kn = *(const u16x8*)&kbase[(size_t)((ct + 1) * 64 + srow) * Dn + scol];
      vn = *(const u16x8*)&vbase[(size_t)srow * Sn + (ct + 1) * 64 + scol];
    }
    #pragma unroll
    for (int grp = 0; grp < 2; ++grp) {
      const int myrow = Q0 + 128 * grp + 16 * w;
      if (ct * 64 > myrow + 14) continue;   // tile fully masked for this group
      // S = Q K^T : out[q][kv], kv = 16j + r16, q = 4g + r
      f32x4 sa[4];
      __builtin_amdgcn_s_setprio(1);
      #pragma unroll
      for (int j = 0; j < 4; ++j) {
        sa[j] = (f32x4){0.f, 0.f, 0.f, 0.f};
        #pragma unroll
        for (int ks = 0; ks < 2; ++ks) {
          bf16x8 kf = *(const bf16x8*)&kl[16 * j + r16][32 * ks + 8 * g];
          sa[j] = __builtin_amdgcn_mfma_f32_16x16x32_bf16(qf[grp][ks], kf, sa[j], 0, 0, 0);
        }
      }
      __builtin_amdgcn_s_setprio(0);
      // scale + strict-causal mask + online softmax (defer-max THR=8)
      const bool needmask = (ct * 64 + 63 >= myrow);
      float p4[4][4];
      #pragma unroll
      for (int j = 0; j < 4; ++j)
        #pragma unroll
        for (int r = 0; r < 4; ++r) {
          float v = sa[j][r] * 0.125f;
          if (needmask && (ct * 64 + 16 * j + r16 >= myrow + 4 * g + r)) v = -3e38f;
          p4[j][r] = v;
        }
      #pragma unroll
      for (int r = 0; r < 4; ++r) {
        float m = fmaxf(fmaxf(p4[0][r], p4[1][r]), fmaxf(p4[2][r], p4[3][r]));
        #pragma unroll
        for (int o = 8; o; o >>= 1) m = fmaxf(m, __shfl_xor(m, o));
        const bool defer = (m <= mrow[grp][r] + 8.f);   // T13
        const float mn = defer ? mrow[grp][r] : m;
        float s = 0.f;
        #pragma unroll
        for (int j = 0; j < 4; ++j) {
          float e = __expf(p4[j][r] - mn);   // masked: -> 0; bounded e^8
          p4[j][r] = e;
          s += e;
        }
        #pragma unroll
        for (int o = 8; o; o >>= 1) s += __shfl_xor(s, o);
        if (defer) {
          lrow[grp][r] += s;
        } else {
          const float sc = __expf(mrow[grp][r] - mn);
          mrow[grp][r] = mn;
          lrow[grp][r] = lrow[grp][r] * sc + s;
          #pragma unroll
          for (int j = 0; j < 4; ++j) oacc[grp][j][r] *= sc;
        }
      }
      // P -> bf16 -> per-wave LDS staging (same-wave DS ordering; reused per group)
      #pragma unroll
      for (int j = 0; j < 4; ++j)
        #pragma unroll
        for (int r = 0; r < 4; ++r)
          pw[w][4 * g + r][16 * j + r16] = f2bf(p4[j][r]);
      // O += P V : out[q][dk], dk = 16j + r16
      __builtin_amdgcn_s_setprio(1);
      #pragma unroll
      for (int ks = 0; ks < 2; ++ks) {
        bf16x8 pa = *(const bf16x8*)&pw[w][r16][32 * ks + 8 * g];
        #pragma unroll
        for (int j = 0; j < 4; ++j) {
          bf16x8 vb = *(const bf16x8*)&vl[16 * j + r16][32 * ks + 8 * g];
          oacc[grp][j] = __builtin_amdgcn_mfma_f32_16x16x32_bf16(pa, vb, oacc[grp][j], 0, 0, 0);
        }
      }
      __builtin_amdgcn_s_setprio(0);
    }
    __syncthreads();               // all waves done reading kl/vl of tile ct
    if (pf) {
      *(u16x8*)&kl[srow][scol] = kn;   // compiler waits the global loads here
      *(u16x8*)&vl[srow][scol] = vn;
      __syncthreads();             // tile ct+1 visible to all waves
    }
  }
  // epilogue: normalize (row 0: l=0 -> zero row, matches reference zero_pad)
  #pragma unroll
  for (int grp = 0; grp < 2; ++grp) {
    const int myrow = Q0 + 128 * grp + 16 * w;
    #pragma unroll
    for (int r = 0; r < 4; ++r) {
      float inv = (lrow[grp][r] > 0.f) ? 1.f / lrow[grp][r] : 0.f;
      #pragma unroll
      for (int j = 0; j < 4; ++j)
        O[(size_t)(b * Sn + myrow + 4 * g + r) * Dn + h * DKn + 16 * j + r16] =
            f2bf(oacc[grp][j][r] * inv);
    }
  }
}

// ---------------- fused residual + bias + LayerNorm (f32 master, small path) ----------------
template<int TBF>
__global__ __launch_bounds__(256) void ln_kernel(
    const float* __restrict__ xin, const void* __restrict__ tin,
    const float* __restrict__ pb, const float* __restrict__ gam,
    const float* __restrict__ bet, float* __restrict__ xout, u16* __restrict__ xbout)
{
  const int row = blockIdx.x;
  const int tid = threadIdx.x;
  const size_t base = (size_t)row * Dn + tid * 4;
  float4 xv = *(const float4*)(xin + base);
  float4 tv;
  if (TBF) {
    u16x4 t4 = *(const u16x4*)((const u16*)tin + base);
    tv = make_float4(bf2f(t4[0]), bf2f(t4[1]), bf2f(t4[2]), bf2f(t4[3]));
  } else {
    tv = *(const float4*)((const float*)tin + base);
  }
  float4 bb = *(const float4*)(pb + tid * 4);
  float v0 = xv.x + tv.x + bb.x, v1 = xv.y + tv.y + bb.y;
  float v2 = xv.z + tv.z + bb.z, v3 = xv.w + tv.w + bb.w;
  float s  = v0 + v1 + v2 + v3;
  float s2 = v0 * v0 + v1 * v1 + v2 * v2 + v3 * v3;
  #pragma unroll
  for (int o = 32; o > 0; o >>= 1) { s += __shfl_xor(s, o); s2 += __shfl_xor(s2, o); }
  __shared__ float rs[4], rs2[4];
  const int wid = tid >> 6;
  if ((tid & 63) == 0) { rs[wid] = s; rs2[wid] = s2; }
  __syncthreads();
  s  = rs[0] + rs[1] + rs[2] + rs[3];
  s2 = rs2[0] + rs2[1] + rs2[2] + rs2[3];
  const float mean = s * (1.f / Dn);
  const float var  = s2 * (1.f / Dn) - mean * mean;
  const float rstd = rsqrtf(fmaxf(var, 0.f) + 1e-5f);
  float4 gv = *(const float4*)(gam + tid * 4);
  float4 bv = *(const float4*)(bet + tid * 4);
  float o0 = (v0 - mean) * rstd * gv.x + bv.x;
  float o1 = (v1 - mean) * rstd * gv.y + bv.y;
  float o2 = (v2 - mean) * rstd * gv.z + bv.z;
  float o3 = (v3 - mean) * rstd * gv.w + bv.w;
  *(float4*)(xout + base) = make_float4(o0, o1, o2, o3);
  u16x4 ub = { f2bf(o0), f2bf(o1), f2bf(o2), f2bf(o3) };
  *(u16x4*)(xbout + base) = ub;
}

// ---------------- fused residual + bias + LayerNorm (bf16 master, big path) ----------------
// xin/tin/xbout bf16; FOUT also writes f32 output (final LN only).
template<int FOUT>
__global__ __launch_bounds__(256) void ln_bf_kernel(
    const u16* __restrict__ xin, const u16* __restrict__ tin,
    const float* __restrict__ pb, const float* __restrict__ gam,
    const float* __restrict__ bet, u16* __restrict__ xbout, float* __restrict__ fout)
{
  const int row = blockIdx.x;
  const int tid = threadIdx.x;
  const size_t base = (size_t)row * Dn + tid * 4;
  u16x4 x4 = *(const u16x4*)(xin + base);
  u16x4 t4 = *(const u16x4*)(tin + base);
  float4 bb = *(const float4*)(pb + tid * 4);
  float v0 = bf2f(x4[0]) + bf2f(t4[0]) + bb.x;
  float v1 = bf2f(x4[1]) + bf2f(t4[1]) + bb.y;
  float v2 = bf2f(x4[2]) + bf2f(t4[2]) + bb.z;
  float v3 = bf2f(x4[3]) + bf2f(t4[3]) + bb.w;
  float s  = v0 + v1 + v2 + v3;
  float s2 = v0 * v0 + v1 * v1 + v2 * v2 + v3 * v3;
  #pragma unroll
  for (int o = 32; o > 0; o >>= 1) { s += __shfl_xor(s, o); s2 += __shfl_xor(s2, o); }
  __shared__ float rs[4], rs2[4];
  const int wid = tid >> 6;
  if ((tid & 63) == 0) { rs[wid] = s; rs2[wid] = s2; }
  __syncthreads();
  s  = rs[0] + rs[1] + rs[2] + rs[3];
  s2 = rs2[0] + rs2[1] + rs2[2] + rs2[3];
  const float mean = s * (1.f / Dn);
  const float var  = s2 * (1.f / Dn) - mean * mean;
  const float rstd = rsqrtf(fmaxf(var, 0.f) + 1e-5f);
  float4 gv = *(const float4*)(gam + tid * 4);
  float4 bv = *(const float4*)(bet + tid * 4);
  float o0 = (v0 - mean) * rstd * gv.x + bv.x;
  float o1 = (v1 - mean) * rstd * gv.y + bv.y;
  float o2 = (v2 - mean) * rstd * gv.z + bv.z;
  float o3 = (v3 - mean) * rstd * gv.w + bv.w;
  u16x4 ub = { f2bf(o0), f2bf(o1), f2bf(o2), f2bf(o3) };
  *(u16x4*)(xbout + base) = ub;
  if (FOUT) *(float4*)(fout + base) = make_float4(o0, o1, o2, o3);
}

// ---------------- orchestration ----------------
extern "C" void kernel_launch(void* const* d_in, const int* in_sizes, int n_in,
                              void* d_out, int out_size, void* d_ws, size_t ws_size,
                              hipStream_t stream)
{
  const float* q   = (const float*)d_in[0];
  const float* qa  = (const float*)d_in[1];
  const float* Wk  = (const float*)d_in[2];
  const float* bk  = (const float*)d_in[3];
  const float* Wv  = (const float*)d_in[4];
  const float* bv  = (const float*)d_in[5];
  const float* Wo  = (const float*)d_in[6];
  const float* bo  = (const float*)d_in[7];
  const float* g1  = (const float*)d_in[8];
  const float* be1 = (const float*)d_in[9];
  const float* W1  = (const float*)d_in[10];
  const float* c1  = (const float*)d_in[11];
  const float* W2  = (const float*)d_in[12];
  const float* c2  = (const float*)d_in[13];
  const float* g2  = (const float*)d_in[14];
  const float* be2 = (const float*)d_in[15];
  float* x = (float*)d_out;   // f32 output (big path: written only by final LN)

  const size_t MD  = (size_t)Mn * Dn;
  const size_t MF  = (size_t)Mn * DFFn;
  const size_t WSZ = 3 * (size_t)Dn * Dn * 2 + 2 * (size_t)Dn * DFFn * 2;
  const size_t NEED_SMALL = 5 * MD * 2 + WSZ + 8192;
  const size_t NEED_BIG   = 2 * MD * 2 + MF * 2 + MD * 4 + WSZ + 8192;
  if (ws_size < NEED_SMALL) return;  // diagnostic guard
  const bool big = (ws_size >= NEED_BIG);

  char* wsb = (char*)d_ws;
  size_t off = 0;
  auto take = [&](size_t bytes) -> void* {
    void* r = wsb + off;
    off += (bytes + 255) & ~(size_t)255;
    return r;
  };
  u16 *XB, *YB, *KB, *VT, *VB, *H1 = nullptr;
  float* TMP;
  XB = (u16*)take(MD * 2);
  YB = (u16*)take(MD * 2);
  if (big) {
    H1  = (u16*)take(MF * 2);        // 128 MB; first 96 MB overlaid by KB/VT/VB
    TMP = (float*)take(MD * 4);      // separate (live during W2 which reads H1)
    KB  = H1;
    VT  = H1 + MD;
    VB  = H1 + 2 * MD;
  } else {
    KB  = (u16*)take(MD * 2);
    VT  = (u16*)take(MD * 2);
    VB  = (u16*)take(MD * 2);
    TMP = (float*)KB;                // overlays KB+VT (dead after attn)
  }
  u16* WKT = (u16*)take((size_t)Dn * Dn * 2);
  u16* WVT = (u16*)take((size_t)Dn * Dn * 2);
  u16* WOT = (u16*)take((size_t)Dn * Dn * 2);
  u16* W1T = (u16*)take((size_t)Dn * DFFn * 2);
  u16* W2T = (u16*)take((size_t)Dn * DFFn * 2);
  u16* H1C = VB;                     // small path: FFN hidden chunk overlays VB
  u16* TMPB = (u16*)TMP;             // big path: bf16 pre-LN buffer (overlays TMP region)
  (void)in_sizes; (void)n_in; (void)out_size;

  if (big) pe_add_kernel<0><<<Mn * Dn / 1024, 256, 0, stream>>>(q, qa, x, XB, YB);
  else     pe_add_kernel<1><<<Mn * Dn / 1024, 256, 0, stream>>>(q, qa, x, XB, YB);

  const dim3 g256(Dn / 256, Mn / 256);       // (4,64) = 256 blocks
  const dim3 g256z(Dn / 256, Mn / 256, 2);   // dual K+V projection
  const dim3 gW1(DFFn / 256, Mn / 256);      // (16,64) = 1024 blocks
  for (int l = 0; l < Ln; ++l) {
    const size_t wo = (size_t)l * Dn * Dn;
    const size_t fo = (size_t)l * Dn * DFFn;
    // per-layer weight transposes (bf16 cast): Wk/Wv/Wo fused; W1; W2
    transpose_cast3_kernel<<<dim3(32, 32, 3), 256, 0, stream>>>(
        Wk + wo, Wv + wo, Wo + wo, WKT, WVT, WOT);
    transpose_cast_kernel<<<dim3(128, 32), 256, 0, stream>>>(W1 + fo, W1T, Dn, DFFn);
    transpose_cast_kernel<<<dim3(32, 128), 256, 0, stream>>>(W2 + fo, W2T, DFFn, Dn);

    // K(=Q) and V projections in one dual dispatch; V written head-transposed
    gemm8p_kernel<1,0,0,0,1,1><<<g256z, 512, 0, stream>>>(
        XB, Dn, WKT, Dn, bk + l * Dn, KB, Dn, Mn, Dn, Dn,
        YB, WVT, bv + l * Dn, VT);
    fattn_kernel<<<Bn * Hn * 2, 512, 0, stream>>>(KB, VT, VB);
    if (big) {
      // output projection -> TMPB (bf16), then LN1 on the bf16 residual master
      gemm8p_kernel<0,0,0,0><<<g256, 512, 0, stream>>>(VB, Dn, WOT, Dn, nullptr, TMPB, Dn, Mn, Dn, Dn);
      ln_bf_kernel<0><<<Mn, 256, 0, stream>>>(XB, TMPB, bo + l * Dn, g1 + l * Dn, be1 + l * Dn, XB, nullptr);
      gemm8p_kernel<1,1,0,0><<<gW1, 512, 0, stream>>>(
          XB, Dn, W1T, Dn, c1 + l * DFFn, H1, DFFn, Mn, DFFn, Dn);
      gemm8p_kernel<0,0,0,0><<<g256, 512, 0, stream>>>(
          H1, DFFn, W2T, DFFn, nullptr, TMPB, Dn, Mn, Dn, DFFn);
      if (l == Ln - 1)
        ln_bf_kernel<1><<<Mn, 256, 0, stream>>>(XB, TMPB, c2 + l * Dn, g2 + l * Dn, be2 + l * Dn, XB, x);
      else
        ln_bf_kernel<0><<<Mn, 256, 0, stream>>>(XB, TMPB, c2 + l * Dn, g2 + l * Dn, be2 + l * Dn, XB, nullptr);
    } else {
      // output projection -> TMP (f32), then LN1
      gemm8p_kernel<0,0,1,0><<<g256, 512, 0, stream>>>(VB, Dn, WOT, Dn, nullptr, TMP, Dn, Mn, Dn, Dn);
      ln_kernel<0><<<Mn, 256, 0, stream>>>(x, TMP, bo + l * Dn, g1 + l * Dn, be1 + l * Dn, x, XB);
      for (int ci = 0; ci < 4; ++ci) {
        gemm8p_kernel<1,1,0,0><<<g256, 512, 0, stream>>>(
            XB, Dn, W1T + (size_t)ci * Dn * Dn, Dn, c1 + l * DFFn + ci * Dn, H1C, Dn, Mn, Dn, Dn);
        if (ci == 0)
          gemm8p_kernel<0,0,1,0><<<g256, 512, 0, stream>>>(
              H1C, Dn, W2T + (size_t)ci * Dn, DFFn, nullptr, TMP, Dn, Mn, Dn, Dn);
        else
          gemm8p_kernel<0,0,1,1><<<g256, 512, 0, stream>>>(
              H1C, Dn, W2T + (size_t)ci * Dn, DFFn, nullptr, TMP, Dn, Mn, Dn, Dn);
      }
      ln_kernel<0><<<Mn, 256, 0, stream>>>(x, TMP, c2 + l * Dn, g2 + l * Dn, be2 + l * Dn, x, XB);
    }
  }
}

// Round 16
// 1984.163 us; speedup vs baseline: 1.0597x; 1.0597x over previous
//
#include <hip/hip_runtime.h>

// promptKT 4-layer transformer, MI355X bf16 MFMA implementation.
// Adaptive workspace: big path ~279 MB (full FFN hidden), small path ~191 MB.
// GEMM (R10/R12-verified, frozen): 256x256, BK=64, 8 waves, 1 barrier/K-tile,
// pipelined A/B frags via LDS, XOR-chunk swizzle, fused V head-transpose (VTR).
// fattn (R14-verified, reverted from R15's QBLK=256 which doubled the critical
// path per block): QBLK=128, grid B*H*4; T14 async-stage, T13 defer-max, T5.
// R14: bf16 residual master on big path; final LN also writes f32 d_out.

#define DEV static __device__ __forceinline__

typedef unsigned short u16;
typedef __attribute__((ext_vector_type(4))) unsigned short u16x4;
typedef __attribute__((ext_vector_type(8))) unsigned short u16x8;
typedef __attribute__((ext_vector_type(8))) short bf16x8;
typedef __attribute__((ext_vector_type(4))) float f32x4;

static constexpr int Bn = 32, Sn = 512, Dn = 1024, Hn = 16, Ln = 4, DFFn = 4096, DKn = 64;
static constexpr int Mn = Bn * Sn; // 16384 rows

DEV u16 f2bf(float f) {
  unsigned u = __float_as_uint(f);
  u += 0x7FFFu + ((u >> 16) & 1u);   // round-nearest-even (no NaN inputs here)
  return (u16)(u >> 16);
}
DEV float bf2f(u16 v) { return __uint_as_float((unsigned)v << 16); }

DEV void gload_lds16(const void* g, void* l) {
  __builtin_amdgcn_global_load_lds((const __attribute__((address_space(1))) void*)g,
                                   (__attribute__((address_space(3))) void*)l, 16, 0, 0);
}

DEV void barf() {
  asm volatile("" ::: "memory");
  __builtin_amdgcn_s_barrier();
  asm volatile("" ::: "memory");
}

// ---------------- positional embedding + input casts ----------------
// WX: also write f32 x master (small-ws path only).
template<int WX>
__global__ __launch_bounds__(256) void pe_add_kernel(
    const float* __restrict__ q, const float* __restrict__ qa,
    float* __restrict__ x, u16* __restrict__ xb, u16* __restrict__ yb)
{
  size_t i4 = ((size_t)blockIdx.x * 256 + threadIdx.x) * 4;
  int d0 = (int)(i4 & (Dn - 1));
  int s  = (int)((i4 >> 10) & (Sn - 1));
  float p = (float)s;
  const float LC = 0.0089944730195f;  // ln(10000)/1024
  float a0 = p * expf(-LC * (float)d0);
  float a2 = p * expf(-LC * (float)(d0 + 2));
  float pe0 = sinf(a0), pe1 = cosf(a0), pe2 = sinf(a2), pe3 = cosf(a2);
  const float4 qv = *(const float4*)(q + i4);
  const float4 av = *(const float4*)(qa + i4);
  float x0 = qv.x + pe0, x1 = qv.y + pe1, x2 = qv.z + pe2, x3 = qv.w + pe3;
  float y0 = av.x + pe0, y1 = av.y + pe1, y2 = av.z + pe2, y3 = av.w + pe3;
  if (WX) *(float4*)(x + i4) = make_float4(x0, x1, x2, x3);
  u16x4 xv4 = { f2bf(x0), f2bf(x1), f2bf(x2), f2bf(x3) };
  u16x4 yv4 = { f2bf(y0), f2bf(y1), f2bf(y2), f2bf(y3) };
  *(u16x4*)(xb + i4) = xv4;
  *(u16x4*)(yb + i4) = yv4;
}

// ---------------- weight transpose + f32->bf16 cast ----------------
// in: (R, C) f32 row-major ; out: (C, R) bf16 row-major
__global__ __launch_bounds__(256) void transpose_cast_kernel(
    const float* __restrict__ in, u16* __restrict__ out, int R, int C)
{
  __shared__ float t[32][33];
  int tx = threadIdx.x & 31, ty = threadIdx.x >> 5;
  int c0 = blockIdx.x * 32, r0 = blockIdx.y * 32;
  #pragma unroll
  for (int i = 0; i < 4; ++i)
    t[ty + i * 8][tx] = in[(size_t)(r0 + ty + i * 8) * C + c0 + tx];
  __syncthreads();
  #pragma unroll
  for (int i = 0; i < 4; ++i) {
    int rr = ty + i * 8;
    out[(size_t)(c0 + rr) * R + r0 + tx] = f2bf(t[tx][rr]);
  }
}

// 3x (1024,1024) transposes in one dispatch (z selects which weight)
__global__ __launch_bounds__(256) void transpose_cast3_kernel(
    const float* __restrict__ i0, const float* __restrict__ i1, const float* __restrict__ i2,
    u16* __restrict__ o0, u16* __restrict__ o1, u16* __restrict__ o2)
{
  const int z = blockIdx.z;
  const float* in = (z == 0) ? i0 : (z == 1) ? i1 : i2;
  u16* out = (z == 0) ? o0 : (z == 1) ? o1 : o2;
  __shared__ float t[32][33];
  int tx = threadIdx.x & 31, ty = threadIdx.x >> 5;
  int c0 = blockIdx.x * 32, r0 = blockIdx.y * 32;
  #pragma unroll
  for (int i = 0; i < 4; ++i)
    t[ty + i * 8][tx] = in[(size_t)(r0 + ty + i * 8) * Dn + c0 + tx];
  __syncthreads();
  #pragma unroll
  for (int i = 0; i < 4; ++i) {
    int rr = ty + i * 8;
    out[(size_t)(c0 + rr) * Dn + r0 + tx] = f2bf(t[tx][rr]);
  }
}

// ------------- bf16 GEMM 256x256, BK=64, 8 waves, 1-barrier/tile pipelined -------------
// C(M,N) = A(M,K) * BT(N,K)^T (+bias)(+relu)(+acc). M,N mult of 256, K of 64.
// LDS: 2 bufs x (A[256][64] + B[256][64]) bf16 = 128 KB, 1 block/CU.
// XOR-chunk swizzle: phys 16B-chunk c of row r holds logical chunk c^(r&7)
// (linear gload_lds dest + inverse-swizzled global source + swizzled ds_read).
// DUAL: blockIdx.z==1 switches to (A2,BT2,bias2,Cout2). VTR: z==1 plane writes
// head-transposed (B,H,DK,S) bf16 (fused vtrans).
template<int BIAS, int RELU, int F32OUT, int ACC, int DUAL = 0, int VTR = 0>
__global__ __launch_bounds__(512, 2) void gemm8p_kernel(
    const u16* __restrict__ A, int lda,
    const u16* __restrict__ BT, int ldb,
    const float* __restrict__ bias,
    void* __restrict__ Cout, int ldc,
    int M, int N, int K,
    const u16* A2 = nullptr, const u16* BT2 = nullptr,
    const float* bias2 = nullptr, void* Cout2 = nullptr)
{
  if (DUAL && blockIdx.z) { A = A2; BT = BT2; bias = bias2; Cout = Cout2; }
  const bool vtr = VTR && DUAL && blockIdx.z;
  __shared__ u16 lds[2][2][16384];   // [buf][A=0|B=1][256 rows x 64 k]
  const int tid = threadIdx.x;
  const int lane = tid & 63, wid = tid >> 6;
  const int g = lane >> 4, r16 = lane & 15;
  const int wm = wid >> 2, wn = wid & 3;   // 2(M) x 4(N) waves; per-wave C: 128x64

  // XCD-chunked block swizzle (bijective; per-z-plane grid size % 8 == 0)
  const int nwgx = N >> 8;
  const int nwg = gridDim.x * gridDim.y;
  const int flat = blockIdx.y * gridDim.x + blockIdx.x;
  const int cpx = nwg >> 3;
  const int logical = (flat & 7) * cpx + (flat >> 3);
  const int n0 = (logical % nwgx) << 8;
  const int m0 = (logical / nwgx) << 8;

  f32x4 acc[8][4];
  #pragma unroll
  for (int i = 0; i < 8; ++i)
    #pragma unroll
    for (int j = 0; j < 4; ++j) acc[i][j] = (f32x4){0.f, 0.f, 0.f, 0.f};

  // staging: thread covers (row rr, 16B chunk ck); source col chunk = ck ^ (rr&7)
  const int rr = tid >> 3, ck = tid & 7;
  const int scol = ((ck ^ (rr & 7)) << 3);
  const u16* Asrc = A  + (size_t)(m0 + rr) * lda + scol;
  const u16* Bsrc = BT + (size_t)(n0 + rr) * ldb + scol;
  const int eds = rr * 64 + ck * 8;       // linear element offset (== tid*8)
  const size_t a64 = (size_t)64 * lda, b64 = (size_t)64 * ldb;

  // unit h: 0 = A rows 0-127, 1 = A rows 128-255, 2 = B rows 0-127, 3 = B rows 128-255
  #define STG(p, h, t) do {                                                  \
    if ((h) < 2) {                                                           \
      const u16* s_ = Asrc + (size_t)((h) * 128) * lda + (t) * 64;           \
      gload_lds16(s_,       &lds[p][0][eds + (h) * 8192]);                   \
      gload_lds16(s_ + a64, &lds[p][0][eds + (h) * 8192 + 4096]);            \
    } else {                                                                 \
      const u16* s_ = Bsrc + (size_t)(((h) - 2) * 128) * ldb + (t) * 64;     \
      gload_lds16(s_,       &lds[p][1][eds + ((h) - 2) * 8192]);             \
      gload_lds16(s_ + b64, &lds[p][1][eds + ((h) - 2) * 8192 + 4096]);      \
    }                                                                        \
  } while (0)

  // ds_read swizzled chunk offsets (elements): frag (ks,g) -> chunk (ks*4+g)^(r16&7)
  const int c0 = ((g ^ (r16 & 7)) << 3);
  const int c1 = (((4 + g) ^ (r16 & 7)) << 3);
  const int arow = wm * 128 + r16;
  const int brow = wn * 64 + r16;

  #define LDA2(p, q, af) do {                                                        \
    af[0][0] = *(const bf16x8*)&lds[p][0][(arow + (2*(q))   * 16) * 64 + c0];        \
    af[0][1] = *(const bf16x8*)&lds[p][0][(arow + (2*(q))   * 16) * 64 + c1];        \
    af[1][0] = *(const bf16x8*)&lds[p][0][(arow + (2*(q)+1) * 16) * 64 + c0];        \
    af[1][1] = *(const bf16x8*)&lds[p][0][(arow + (2*(q)+1) * 16) * 64 + c1];        \
  } while (0)

  // ks-outer: 8 independent MFMAs between successive writes of the same acc
  #define MMQ(q, af, bf) do {                                                        \
    __builtin_amdgcn_s_setprio(1);                                                   \
    _Pragma("unroll")                                                                \
    for (int ks = 0; ks < 2; ++ks)                                                   \
      _Pragma("unroll")                                                              \
      for (int i2 = 0; i2 < 2; ++i2)                                                 \
        _Pragma("unroll")                                                            \
        for (int j = 0; j < 4; ++j)                                                  \
          acc[2*(q)+i2][j] = __builtin_amdgcn_mfma_f32_16x16x32_bf16(af[i2][ks], bf[j][ks], acc[2*(q)+i2][j], 0, 0, 0); \
    __builtin_amdgcn_s_setprio(0);                                                   \
  } while (0)

  const int nt = K >> 6;
  // prologue: stage tile 0 fully, drain, barrier
  STG(0, 0, 0); STG(0, 1, 0); STG(0, 2, 0); STG(0, 3, 0);
  asm volatile("s_waitcnt vmcnt(0)" ::: "memory");
  barf();

  for (int t = 0; t < nt; ++t) {
    const int p = t & 1;
    const bool pf = (t + 1 < nt);
    bf16x8 bf[4][2], af[2][2], ag[2][2];
    // B fragments (8 reads) + A quad 0 (4 reads); STG units interleaved for lead time
    #pragma unroll
    for (int j = 0; j < 4; ++j) {
      bf[j][0] = *(const bf16x8*)&lds[p][1][(brow + j * 16) * 64 + c0];
      bf[j][1] = *(const bf16x8*)&lds[p][1][(brow + j * 16) * 64 + c1];
    }
    LDA2(p, 0, af);
    if (pf) { STG(p ^ 1, 0, t + 1); STG(p ^ 1, 1, t + 1); }
    MMQ(0, af, bf);
    LDA2(p, 1, ag);           // overlaps MMQ(0) retire / MMQ(1) waits only these
    if (pf) STG(p ^ 1, 2, t + 1);
    MMQ(1, ag, bf);
    LDA2(p, 2, af);
    if (pf) STG(p ^ 1, 3, t + 1);
    MMQ(2, af, bf);
    LDA2(p, 3, ag);
    MMQ(3, ag, bf);
    // tile-end fences: all buf-p ds_reads complete (next tile's STG overwrites
    // buf p) and all U(t+1) staging landed (next tile reads buf p^1).
    asm volatile("s_waitcnt lgkmcnt(0)" ::: "memory");
    asm volatile("s_waitcnt vmcnt(0)" ::: "memory");
    barf();
  }
  #undef STG
  #undef LDA2
  #undef MMQ

  #pragma unroll
  for (int i = 0; i < 8; ++i) {
    const int rb = m0 + wm * 128 + i * 16 + 4 * g;
    #pragma unroll
    for (int j = 0; j < 4; ++j) {
      const int col = n0 + wn * 64 + j * 16 + r16;
      float badd = BIAS ? bias[col] : 0.f;
      if (vtr) {
        // head-transposed write: (B,H,DK,S), 4 consecutive s -> one u16x4
        u16x4 pk;
        #pragma unroll
        for (int r = 0; r < 4; ++r) pk[r] = f2bf(acc[i][j][r] + badd);
        const int h_ = col >> 6, dk = col & 63;
        const int b_ = rb >> 9, s0 = rb & (Sn - 1);
        *(u16x4*)&((u16*)Cout)[(((size_t)(b_ * Hn + h_) * DKn + dk) << 9) + s0] = pk;
      } else {
        #pragma unroll
        for (int r = 0; r < 4; ++r) {
          size_t off = (size_t)(rb + r) * ldc + col;
          float v = acc[i][j][r] + badd;
          if (RELU) v = fmaxf(v, 0.f);
          if (F32OUT) {
            float* Cf = (float*)Cout;
            if (ACC) v += Cf[off];
            Cf[off] = v;
          } else {
            ((u16*)Cout)[off] = f2bf(v);
          }
        }
      }
    }
  }
}

// ---------------- flash attention: strictly-causal softmax(QK^T/8)V ----------------
// Kb serves as both Q and K (kq_same). Vt is (B,H,DK,S). O is (B*S, D) bf16.
// Block: one (b,h) x 128 Q-rows; 8 waves x 16 Q-rows; KV tiles of 64.
// T14: tile ct+1 global->reg loads issued before compute of ct (latency hides),
// ds_write after post-compute barrier. T13: defer-max THR=8. T5: setprio.
__global__ __launch_bounds__(512) void fattn_kernel(
    const u16* __restrict__ Kb, const u16* __restrict__ Vt, u16* __restrict__ O)
{
  __shared__ u16 kl[64][72];      // K tile: [kv][dk]
  __shared__ u16 vl[64][72];      // V tile: [dk][kv]
  __shared__ u16 pw[8][16][72];   // per-wave P staging: [q][kv]
  const int idx = blockIdx.x;     // B*H*4
  const int qt = idx & 3;
  const int h  = (idx >> 2) & 15;
  const int b  = idx >> 6;
  const int Q0 = qt * 128;
  const int tid = threadIdx.x;
  const int lane = tid & 63, w = tid >> 6;
  const int g = lane >> 4, r16 = lane & 15;
  const int myrow = Q0 + 16 * w;  // wave's first Q row

  // Q fragment in registers (wave w owns rows myrow .. myrow+15)
  bf16x8 qf[2];
  {
    const u16* qrow = &Kb[(size_t)(b * Sn + myrow + r16) * Dn + h * DKn];
    qf[0] = *(const bf16x8*)(qrow + 8 * g);
    qf[1] = *(const bf16x8*)(qrow + 32 + 8 * g);
  }
  f32x4 oacc[4];
  float mrow[4], lrow[4];
  #pragma unroll
  for (int j = 0; j < 4; ++j) oacc[j] = (f32x4){0.f, 0.f, 0.f, 0.f};
  #pragma unroll
  for (int r = 0; r < 4; ++r) { mrow[r] = -1e30f; lrow[r] = 0.f; }

  const int srow = tid >> 3;          // 0..63
  const int scol = (tid & 7) * 8;
  const u16* kbase = Kb + (size_t)(b * Sn) * Dn + h * DKn;
  const u16* vbase = Vt + (size_t)(b * Hn + h) * DKn * Sn;
  const int ctmax = 2 * qt + 1;

  // prologue: stage tile 0
  {
    u16x8 k0 = *(const u16x8*)&kbase[(size_t)srow * Dn + scol];
    u16x8 v0 = *(const u16x8*)&vbase[(size_t)srow * Sn + scol];
    *(u16x8*)&kl[srow][scol] = k0;
    *(u16x8*)&vl[srow][scol] = v0;
  }
  __syncthreads();

  for (int ct = 0; ct <= ctmax; ++ct) {
    // T14: issue next tile's loads now; consumed only after the next barrier.
    u16x8 kn, vn;
    const bool pf = (ct + 1 <= ctmax);
    if (pf) {
      kn = *(const u16x8*)&kbase[(size_t)((ct + 1) * 64 + srow) * Dn + scol];
      vn = *(const u16x8*)&vbase[(size_t)srow * Sn + (ct + 1) * 64 + scol];
    }
    if (ct * 64 <= myrow + 14) {   // tile has unmasked columns for this wave
      // S = Q K^T : out[q][kv], kv = 16j + r16, q = 4g + r
      f32x4 sa[4];
      __builtin_amdgcn_s_setprio(1);
      #pragma unroll
      for (int j = 0; j < 4; ++j) {
        sa[j] = (f32x4){0.f, 0.f, 0.f, 0.f};
        #pragma unroll
        for (int ks = 0; ks < 2; ++ks) {
          bf16x8 kf = *(const bf16x8*)&kl[16 * j + r16][32 * ks + 8 * g];
          sa[j] = __builtin_amdgcn_mfma_f32_16x16x32_bf16(qf[ks], kf, sa[j], 0, 0, 0);
        }
      }
      __builtin_amdgcn_s_setprio(0);
      // scale + strict-causal mask + online softmax (defer-max THR=8)
      const bool needmask = (ct * 64 + 63 >= myrow);
      float p4[4][4];
      #pragma unroll
      for (int j = 0; j < 4; ++j)
        #pragma unroll
        for (int r = 0; r < 4; ++r) {
          float v = sa[j][r] * 0.125f;
          if (needmask && (ct * 64 + 16 * j + r16 >= myrow + 4 * g + r)) v = -3e38f;
          p4[j][r] = v;
        }
      #pragma unroll
      for (int r = 0; r < 4; ++r) {
        float m = fmaxf(fmaxf(p4[0][r], p4[1][r]), fmaxf(p4[2][r], p4[3][r]));
        #pragma unroll
        for (int o = 8; o; o >>= 1) m = fmaxf(m, __shfl_xor(m, o));
        const bool defer = (m <= mrow[r] + 8.f);   // T13: keep old max, skip rescale
        const float mn = defer ? mrow[r] : m;
        float s = 0.f;
        #pragma unroll
        for (int j = 0; j < 4; ++j) {
          float e = __expf(p4[j][r] - mn);   // masked: exp(-3e38 - mn) -> 0; bounded e^8
          p4[j][r] = e;
          s += e;
        }
        #pragma unroll
        for (int o = 8; o; o >>= 1) s += __shfl_xor(s, o);
        if (defer) {
          lrow[r] += s;
        } else {
          const float sc = __expf(mrow[r] - mn);
          mrow[r] = mn;
          lrow[r] = lrow[r] * sc + s;
          #pragma unroll
          for (int j = 0; j < 4; ++j) oacc[j][r] *= sc;
        }
      }
      // P -> bf16 -> per-wave LDS staging (same-wave DS ops in-order; no barrier)
      #pragma unroll
      for (int j = 0; j < 4; ++j)
        #pragma unroll
        for (int r = 0; r < 4; ++r)
          pw[w][4 * g + r][16 * j + r16] = f2bf(p4[j][r]);
      // O += P V : out[q][dk], dk = 16j + r16
      __builtin_amdgcn_s_setprio(1);
      #pragma unroll
      for (int ks = 0; ks < 2; ++ks) {
        bf16x8 pa = *(const bf16x8*)&pw[w][r16][32 * ks + 8 * g];
        #pragma unroll
        for (int j = 0; j < 4; ++j) {
          bf16x8 vb = *(const bf16x8*)&vl[16 * j + r16][32 * ks + 8 * g];
          oacc[j] = __builtin_amdgcn_mfma_f32_16x16x32_bf16(pa, vb, oacc[j], 0, 0, 0);
        }
      }
      __builtin_amdgcn_s_setprio(0);
    }
    __syncthreads();               // all waves done reading kl/vl of tile ct
    if (pf) {
      *(u16x8*)&kl[srow][scol] = kn;   // compiler waits the global loads here
      *(u16x8*)&vl[srow][scol] = vn;
      __syncthreads();             // tile ct+1 visible to all waves
    }
  }
  // epilogue: normalize (row 0: l=0 -> zero row, matches reference zero_pad)
  #pragma unroll
  for (int r = 0; r < 4; ++r) {
    float inv = (lrow[r] > 0.f) ? 1.f / lrow[r] : 0.f;
    #pragma unroll
    for (int j = 0; j < 4; ++j)
      O[(size_t)(b * Sn + myrow + 4 * g + r) * Dn + h * DKn + 16 * j + r16] =
          f2bf(oacc[j][r] * inv);
  }
}

// ---------------- fused residual + bias + LayerNorm (f32 master, small path) ----------------
template<int TBF>
__global__ __launch_bounds__(256) void ln_kernel(
    const float* __restrict__ xin, const void* __restrict__ tin,
    const float* __restrict__ pb, const float* __restrict__ gam,
    const float* __restrict__ bet, float* __restrict__ xout, u16* __restrict__ xbout)
{
  const int row = blockIdx.x;
  const int tid = threadIdx.x;
  const size_t base = (size_t)row * Dn + tid * 4;
  float4 xv = *(const float4*)(xin + base);
  float4 tv;
  if (TBF) {
    u16x4 t4 = *(const u16x4*)((const u16*)tin + base);
    tv = make_float4(bf2f(t4[0]), bf2f(t4[1]), bf2f(t4[2]), bf2f(t4[3]));
  } else {
    tv = *(const float4*)((const float*)tin + base);
  }
  float4 bb = *(const float4*)(pb + tid * 4);
  float v0 = xv.x + tv.x + bb.x, v1 = xv.y + tv.y + bb.y;
  float v2 = xv.z + tv.z + bb.z, v3 = xv.w + tv.w + bb.w;
  float s  = v0 + v1 + v2 + v3;
  float s2 = v0 * v0 + v1 * v1 + v2 * v2 + v3 * v3;
  #pragma unroll
  for (int o = 32; o > 0; o >>= 1) { s += __shfl_xor(s, o); s2 += __shfl_xor(s2, o); }
  __shared__ float rs[4], rs2[4];
  const int wid = tid >> 6;
  if ((tid & 63) == 0) { rs[wid] = s; rs2[wid] = s2; }
  __syncthreads();
  s  = rs[0] + rs[1] + rs[2] + rs[3];
  s2 = rs2[0] + rs2[1] + rs2[2] + rs2[3];
  const float mean = s * (1.f / Dn);
  const float var  = s2 * (1.f / Dn) - mean * mean;
  const float rstd = rsqrtf(fmaxf(var, 0.f) + 1e-5f);
  float4 gv = *(const float4*)(gam + tid * 4);
  float4 bv = *(const float4*)(bet + tid * 4);
  float o0 = (v0 - mean) * rstd * gv.x + bv.x;
  float o1 = (v1 - mean) * rstd * gv.y + bv.y;
  float o2 = (v2 - mean) * rstd * gv.z + bv.z;
  float o3 = (v3 - mean) * rstd * gv.w + bv.w;
  *(float4*)(xout + base) = make_float4(o0, o1, o2, o3);
  u16x4 ub = { f2bf(o0), f2bf(o1), f2bf(o2), f2bf(o3) };
  *(u16x4*)(xbout + base) = ub;
}

// ---------------- fused residual + bias + LayerNorm (bf16 master, big path) ----------------
// xin/tin/xbout bf16; FOUT also writes f32 output (final LN only).
template<int FOUT>
__global__ __launch_bounds__(256) void ln_bf_kernel(
    const u16* __restrict__ xin, const u16* __restrict__ tin,
    const float* __restrict__ pb, const float* __restrict__ gam,
    const float* __restrict__ bet, u16* __restrict__ xbout, float* __restrict__ fout)
{
  const int row = blockIdx.x;
  const int tid = threadIdx.x;
  const size_t base = (size_t)row * Dn + tid * 4;
  u16x4 x4 = *(const u16x4*)(xin + base);
  u16x4 t4 = *(const u16x4*)(tin + base);
  float4 bb = *(const float4*)(pb + tid * 4);
  float v0 = bf2f(x4[0]) + bf2f(t4[0]) + bb.x;
  float v1 = bf2f(x4[1]) + bf2f(t4[1]) + bb.y;
  float v2 = bf2f(x4[2]) + bf2f(t4[2]) + bb.z;
  float v3 = bf2f(x4[3]) + bf2f(t4[3]) + bb.w;
  float s  = v0 + v1 + v2 + v3;
  float s2 = v0 * v0 + v1 * v1 + v2 * v2 + v3 * v3;
  #pragma unroll
  for (int o = 32; o > 0; o >>= 1) { s += __shfl_xor(s, o); s2 += __shfl_xor(s2, o); }
  __shared__ float rs[4], rs2[4];
  const int wid = tid >> 6;
  if ((tid & 63) == 0) { rs[wid] = s; rs2[wid] = s2; }
  __syncthreads();
  s  = rs[0] + rs[1] + rs[2] + rs[3];
  s2 = rs2[0] + rs2[1] + rs2[2] + rs2[3];
  const float mean = s * (1.f / Dn);
  const float var  = s2 * (1.f / Dn) - mean * mean;
  const float rstd = rsqrtf(fmaxf(var, 0.f) + 1e-5f);
  float4 gv = *(const float4*)(gam + tid * 4);
  float4 bv = *(const float4*)(bet + tid * 4);
  float o0 = (v0 - mean) * rstd * gv.x + bv.x;
  float o1 = (v1 - mean) * rstd * gv.y + bv.y;
  float o2 = (v2 - mean) * rstd * gv.z + bv.z;
  float o3 = (v3 - mean) * rstd * gv.w + bv.w;
  u16x4 ub = { f2bf(o0), f2bf(o1), f2bf(o2), f2bf(o3) };
  *(u16x4*)(xbout + base) = ub;
  if (FOUT) *(float4*)(fout + base) = make_float4(o0, o1, o2, o3);
}

// ---------------- orchestration ----------------
extern "C" void kernel_launch(void* const* d_in, const int* in_sizes, int n_in,
                              void* d_out, int out_size, void* d_ws, size_t ws_size,
                              hipStream_t stream)
{
  const float* q   = (const float*)d_in[0];
  const float* qa  = (const float*)d_in[1];
  const float* Wk  = (const float*)d_in[2];
  const float* bk  = (const float*)d_in[3];
  const float* Wv  = (const float*)d_in[4];
  const float* bv  = (const float*)d_in[5];
  const float* Wo  = (const float*)d_in[6];
  const float* bo  = (const float*)d_in[7];
  const float* g1  = (const float*)d_in[8];
  const float* be1 = (const float*)d_in[9];
  const float* W1  = (const float*)d_in[10];
  const float* c1  = (const float*)d_in[11];
  const float* W2  = (const float*)d_in[12];
  const float* c2  = (const float*)d_in[13];
  const float* g2  = (const float*)d_in[14];
  const float* be2 = (const float*)d_in[15];
  float* x = (float*)d_out;   // f32 output (big path: written only by final LN)

  const size_t MD  = (size_t)Mn * Dn;
  const size_t MF  = (size_t)Mn * DFFn;
  const size_t WSZ = 3 * (size_t)Dn * Dn * 2 + 2 * (size_t)Dn * DFFn * 2;
  const size_t NEED_SMALL = 5 * MD * 2 + WSZ + 8192;
  const size_t NEED_BIG   = 2 * MD * 2 + MF * 2 + MD * 4 + WSZ + 8192;
  if (ws_size < NEED_SMALL) return;  // diagnostic guard
  const bool big = (ws_size >= NEED_BIG);

  char* wsb = (char*)d_ws;
  size_t off = 0;
  auto take = [&](size_t bytes) -> void* {
    void* r = wsb + off;
    off += (bytes + 255) & ~(size_t)255;
    return r;
  };
  u16 *XB, *YB, *KB, *VT, *VB, *H1 = nullptr;
  float* TMP;
  XB = (u16*)take(MD * 2);
  YB = (u16*)take(MD * 2);
  if (big) {
    H1  = (u16*)take(MF * 2);        // 128 MB; first 96 MB overlaid by KB/VT/VB
    TMP = (float*)take(MD * 4);      // separate (live during W2 which reads H1)
    KB  = H1;
    VT  = H1 + MD;
    VB  = H1 + 2 * MD;
  } else {
    KB  = (u16*)take(MD * 2);
    VT  = (u16*)take(MD * 2);
    VB  = (u16*)take(MD * 2);
    TMP = (float*)KB;                // overlays KB+VT (dead after attn)
  }
  u16* WKT = (u16*)take((size_t)Dn * Dn * 2);
  u16* WVT = (u16*)take((size_t)Dn * Dn * 2);
  u16* WOT = (u16*)take((size_t)Dn * Dn * 2);
  u16* W1T = (u16*)take((size_t)Dn * DFFn * 2);
  u16* W2T = (u16*)take((size_t)Dn * DFFn * 2);
  u16* H1C = VB;                     // small path: FFN hidden chunk overlays VB
  u16* TMPB = (u16*)TMP;             // big path: bf16 pre-LN buffer (overlays TMP region)
  (void)in_sizes; (void)n_in; (void)out_size;

  if (big) pe_add_kernel<0><<<Mn * Dn / 1024, 256, 0, stream>>>(q, qa, x, XB, YB);
  else     pe_add_kernel<1><<<Mn * Dn / 1024, 256, 0, stream>>>(q, qa, x, XB, YB);

  const dim3 g256(Dn / 256, Mn / 256);       // (4,64) = 256 blocks
  const dim3 g256z(Dn / 256, Mn / 256, 2);   // dual K+V projection
  const dim3 gW1(DFFn / 256, Mn / 256);      // (16,64) = 1024 blocks
  for (int l = 0; l < Ln; ++l) {
    const size_t wo = (size_t)l * Dn * Dn;
    const size_t fo = (size_t)l * Dn * DFFn;
    // per-layer weight transposes (bf16 cast): Wk/Wv/Wo fused; W1; W2
    transpose_cast3_kernel<<<dim3(32, 32, 3), 256, 0, stream>>>(
        Wk + wo, Wv + wo, Wo + wo, WKT, WVT, WOT);
    transpose_cast_kernel<<<dim3(128, 32), 256, 0, stream>>>(W1 + fo, W1T, Dn, DFFn);
    transpose_cast_kernel<<<dim3(32, 128), 256, 0, stream>>>(W2 + fo, W2T, DFFn, Dn);

    // K(=Q) and V projections in one dual dispatch; V written head-transposed
    gemm8p_kernel<1,0,0,0,1,1><<<g256z, 512, 0, stream>>>(
        XB, Dn, WKT, Dn, bk + l * Dn, KB, Dn, Mn, Dn, Dn,
        YB, WVT, bv + l * Dn, VT);
    fattn_kernel<<<Bn * Hn * 4, 512, 0, stream>>>(KB, VT, VB);
    if (big) {
      // output projection -> TMPB (bf16), then LN1 on the bf16 residual master
      gemm8p_kernel<0,0,0,0><<<g256, 512, 0, stream>>>(VB, Dn, WOT, Dn, nullptr, TMPB, Dn, Mn, Dn, Dn);
      ln_bf_kernel<0><<<Mn, 256, 0, stream>>>(XB, TMPB, bo + l * Dn, g1 + l * Dn, be1 + l * Dn, XB, nullptr);
      gemm8p_kernel<1,1,0,0><<<gW1, 512, 0, stream>>>(
          XB, Dn, W1T, Dn, c1 + l * DFFn, H1, DFFn, Mn, DFFn, Dn);
      gemm8p_kernel<0,0,0,0><<<g256, 512, 0, stream>>>(
          H1, DFFn, W2T, DFFn, nullptr, TMPB, Dn, Mn, Dn, DFFn);
      if (l == Ln - 1)
        ln_bf_kernel<1><<<Mn, 256, 0, stream>>>(XB, TMPB, c2 + l * Dn, g2 + l * Dn, be2 + l * Dn, XB, x);
      else
        ln_bf_kernel<0><<<Mn, 256, 0, stream>>>(XB, TMPB, c2 + l * Dn, g2 + l * Dn, be2 + l * Dn, XB, nullptr);
    } else {
      // output projection -> TMP (f32), then LN1
      gemm8p_kernel<0,0,1,0><<<g256, 512, 0, stream>>>(VB, Dn, WOT, Dn, nullptr, TMP, Dn, Mn, Dn, Dn);
      ln_kernel<0><<<Mn, 256, 0, stream>>>(x, TMP, bo + l * Dn, g1 + l * Dn, be1 + l * Dn, x, XB);
      for (int ci = 0; ci < 4; ++ci) {
        gemm8p_kernel<1,1,0,0><<<g256, 512, 0, stream>>>(
            XB, Dn, W1T + (size_t)ci * Dn * Dn, Dn, c1 + l * DFFn + ci * Dn, H1C, Dn, Mn, Dn, Dn);
        if (ci == 0)
          gemm8p_kernel<0,0,1,0><<<g256, 512, 0, stream>>>(
              H1C, Dn, W2T + (size_t)ci * Dn, DFFn, nullptr, TMP, Dn, Mn, Dn, Dn);
        else
          gemm8p_kernel<0,0,1,1><<<g256, 512, 0, stream>>>(
              H1C, Dn, W2T + (size_t)ci * Dn, DFFn, nullptr, TMP, Dn, Mn, Dn, Dn);
      }
      ln_kernel<0><<<Mn, 256, 0, stream>>>(x, TMP, c2 + l * Dn, g2 + l * Dn, be2 + l * Dn, x, XB);
    }
  }
}